// Round 1
// baseline (331.711 us; speedup 1.0000x reference)
//
#include <hip/hip_runtime.h>
#include <hip/hip_bf16.h>
#include <math.h>

typedef unsigned short u16;
typedef __bf16 bf16;
typedef __bf16 bf16x8 __attribute__((ext_vector_type(8)));
typedef float f32x4 __attribute__((ext_vector_type(4)));
typedef u16 u16x4 __attribute__((ext_vector_type(4)));
typedef u16 u16x8 __attribute__((ext_vector_type(8)));

// scale = 1/sqrt(64) * log2(e)  (folded into Q; softmax uses exp2)
#define QSCALE 0.1803368801111204f

// round-to-nearest-even fp32 -> bf16 bits
static __device__ __forceinline__ u16 f2b(float f) {
  union { float f; unsigned u; } x; x.f = f;
  unsigned r = x.u + 0x7fffu + ((x.u >> 16) & 1u);
  return (u16)(r >> 16);
}

static __device__ __forceinline__ f32x4 mfma16(u16x8 a, u16x8 b, f32x4 c) {
  return __builtin_amdgcn_mfma_f32_16x16x32_bf16(
      __builtin_bit_cast(bf16x8, a), __builtin_bit_cast(bf16x8, b), c, 0, 0, 0);
}

// async global->LDS, 16B per lane; LDS ptr must be wave-uniform
static __device__ __forceinline__ void glds16(const u16* g, u16* l) {
  __builtin_amdgcn_global_load_lds(
      (const __attribute__((address_space(1))) void*)g,
      (__attribute__((address_space(3))) void*)l, 16, 0, 0);
}

// Swizzled LDS read: tiles have 64-u16 (128B) rows = 8 slots of 16B, slot ^= row&7
static __device__ __forceinline__ u16x8 ldsrd(const u16* base, int row, int slot) {
  return *(const u16x8*)(base + row * 64 + ((slot ^ (row & 7)) * 8));
}

__global__ void cast_f32_bf16(const float* __restrict__ src, u16* __restrict__ dst, int n4) {
  int i = blockIdx.x * blockDim.x + threadIdx.x;
  int stride = gridDim.x * blockDim.x;
  for (; i < n4; i += stride) {
    f32x4 v = ((const f32x4*)src)[i];
    u16x4 o;
#pragma unroll
    for (int r = 0; r < 4; r++) o[r] = f2b(v[r]);
    ((u16x4*)dst)[i] = o;
  }
}

// C = A @ B^T (+bias). A [M][K] bf16, B [N][K] bf16. 128x128 tile, BK=64, 256 thr.
// Swapped MFMA: lane holds C^T[n=...+4g+reg][m=...+c] -> packed stores along n.
// MODE 0: QKV epilogue (Q scaled bf16; K,V fp32 to d_out + bf16 K / bf16 V^T to ws)
// MODE 1: out-proj epilogue (fp32 to d_out)
template<int MODE>
__global__ void gemm_bt(const u16* __restrict__ A, const u16* __restrict__ B,
                        const float* __restrict__ b0, const float* __restrict__ b1,
                        const float* __restrict__ b2,
                        float* __restrict__ outF,
                        u16* __restrict__ qs, u16* __restrict__ kb, u16* __restrict__ vt,
                        int K) {
  __shared__ u16 As[128 * 64];
  __shared__ u16 Bs[128 * 64];
  const int t = threadIdx.x, w = t >> 6, l = t & 63;
  const int c = l & 15, g = l >> 4;
  const int n0 = blockIdx.x * 128, m0 = blockIdx.y * 128;
  const int nrow0 = (w >> 1) * 64, mrow0 = (w & 1) * 64;
  const int srow = l >> 3, sslot = l & 7;

  f32x4 acc[4][4];
  f32x4 z = {0.f, 0.f, 0.f, 0.f};
#pragma unroll
  for (int i = 0; i < 4; i++)
#pragma unroll
    for (int j = 0; j < 4; j++) acc[i][j] = z;

  for (int kt = 0; kt < K; kt += 64) {
#pragma unroll
    for (int p = 0; p < 4; p++) {
      int row = p * 32 + w * 8 + srow;
      int ss = sslot ^ (row & 7);  // pre-swizzled source, linear LDS dest
      glds16(A + (size_t)(m0 + row) * K + kt + ss * 8, &As[p * 2048 + w * 512]);
      glds16(B + (size_t)(n0 + row) * K + kt + ss * 8, &Bs[p * 2048 + w * 512]);
    }
    __syncthreads();
#pragma unroll
    for (int ks = 0; ks < 2; ks++) {
      u16x8 af[4], bf[4];
#pragma unroll
      for (int nj = 0; nj < 4; nj++) af[nj] = ldsrd(Bs, nrow0 + 16 * nj + c, g + 4 * ks);
#pragma unroll
      for (int mi = 0; mi < 4; mi++) bf[mi] = ldsrd(As, mrow0 + 16 * mi + c, g + 4 * ks);
#pragma unroll
      for (int nj = 0; nj < 4; nj++)
#pragma unroll
        for (int mi = 0; mi < 4; mi++) acc[nj][mi] = mfma16(af[nj], bf[mi], acc[nj][mi]);
    }
    __syncthreads();
  }

#pragma unroll
  for (int nj = 0; nj < 4; nj++) {
#pragma unroll
    for (int mi = 0; mi < 4; mi++) {
      int n = n0 + nrow0 + 16 * nj + 4 * g;   // 4 consecutive n (reg 0..3)
      int m = m0 + mrow0 + 16 * mi + c;
      f32x4 v = acc[nj][mi];
      if (MODE == 1) {
        f32x4 bb = *(const f32x4*)(b0 + n);
        v += bb;
        *(f32x4*)(outF + (size_t)m * 1024 + n) = v;
      } else {
        if (n < 1024) {              // Q -> scaled bf16
          f32x4 bb = *(const f32x4*)(b0 + n);
          v += bb;
          u16x4 q;
#pragma unroll
          for (int r = 0; r < 4; r++) q[r] = f2b(v[r] * QSCALE);
          *(u16x4*)(qs + (size_t)m * 1024 + n) = q;
        } else if (n < 1280) {       // K -> fp32 d_out + bf16 ws [kh][t][d]
          int nn = n - 1024, khh = nn >> 6, d = nn & 63;
          f32x4 bb = *(const f32x4*)(b1 + nn);
          v += bb;
          *(f32x4*)(outF + (size_t)4194304 + (size_t)(khh * 4096 + m) * 64 + d) = v;
          u16x4 kq;
#pragma unroll
          for (int r = 0; r < 4; r++) kq[r] = f2b(v[r]);
          *(u16x4*)(kb + (size_t)(khh * 4096 + m) * 64 + d) = kq;
        } else {                     // V -> fp32 d_out + bf16 ws TRANSPOSED [kh][d][t]
          int nn = n - 1280, khh = nn >> 6, d = nn & 63;
          f32x4 bb = *(const f32x4*)(b2 + nn);
          v += bb;
          *(f32x4*)(outF + (size_t)5242880 + (size_t)(khh * 4096 + m) * 64 + d) = v;
#pragma unroll
          for (int r = 0; r < 4; r++) vt[(size_t)(khh * 64 + d + r) * 4096 + m] = f2b(v[r]);
        }
      }
    }
  }
}

// Flash attention fwd: grid (32 q-tiles, 16 heads), 256 thr = 4 waves x 32 q-rows.
// Swapped QK^T -> lane owns q-row (softmax = 2 shuffles); swapped PV -> O^T matches
// lane-local softmax state; P round-trips through per-wave swizzled LDS.
__global__ void attn_fwd(const u16* __restrict__ qs, const u16* __restrict__ kb,
                         const u16* __restrict__ vt, u16* __restrict__ att) {
  __shared__ u16 Ks[64 * 64];     // [key][d] swz
  __shared__ u16 Vs[64 * 64];     // [d][key] swz (V^T tile)
  __shared__ u16 Ps[4][32 * 64];  // per-wave [q][key] swz
  const int h = blockIdx.y, kh = h >> 2;
  const int q0 = blockIdx.x * 128;
  const int t = threadIdx.x, w = t >> 6, l = t & 63;
  const int c = l & 15, g = l >> 4;
  const int srow = l >> 3, sslot = l & 7;

  const u16* kbase = kb + (size_t)kh * 4096 * 64;
  const u16* vbase = vt + (size_t)kh * 64 * 4096;

  // Q fragments (B-role): Q[q0+w*32+16qi+c][8g+32ks+j], scale pre-folded
  u16x8 qf[2][2];
#pragma unroll
  for (int qi = 0; qi < 2; qi++)
#pragma unroll
    for (int ks = 0; ks < 2; ks++)
      qf[qi][ks] = *(const u16x8*)(qs + (size_t)(q0 + w * 32 + 16 * qi + c) * 1024 +
                                   h * 64 + g * 8 + ks * 32);

  f32x4 o[2][4];  // O^T acc: [qi][dj], lane: rows d=16dj+4g+reg, col q=16qi+c
  f32x4 z = {0.f, 0.f, 0.f, 0.f};
#pragma unroll
  for (int qi = 0; qi < 2; qi++)
#pragma unroll
    for (int dj = 0; dj < 4; dj++) o[qi][dj] = z;
  float m_r[2] = {-INFINITY, -INFINITY};
  float l_r[2] = {0.f, 0.f};

  for (int kv = 0; kv < 4096; kv += 64) {
#pragma unroll
    for (int p = 0; p < 2; p++) {
      int row = p * 32 + w * 8 + srow;
      int ss = sslot ^ (row & 7);
      glds16(kbase + (size_t)(kv + row) * 64 + ss * 8, &Ks[p * 2048 + w * 512]);
      glds16(vbase + (size_t)row * 4096 + kv + ss * 8, &Vs[p * 2048 + w * 512]);
    }
    __syncthreads();

    // S^T = mfma(K, Q): lane holds S[q=16qi+c][k=16kj+4g+reg]
    f32x4 s[4][2];
#pragma unroll
    for (int kj = 0; kj < 4; kj++)
#pragma unroll
      for (int qi = 0; qi < 2; qi++) s[kj][qi] = z;
#pragma unroll
    for (int ks = 0; ks < 2; ks++) {
      u16x8 kf[4];
#pragma unroll
      for (int kj = 0; kj < 4; kj++) kf[kj] = ldsrd(Ks, 16 * kj + c, g + 4 * ks);
#pragma unroll
      for (int kj = 0; kj < 4; kj++)
#pragma unroll
        for (int qi = 0; qi < 2; qi++) s[kj][qi] = mfma16(kf[kj], qf[qi][ks], s[kj][qi]);
    }

    // online softmax (exp2 domain), pack P -> per-wave LDS
#pragma unroll
    for (int qi = 0; qi < 2; qi++) {
      float pm = -INFINITY;
#pragma unroll
      for (int kj = 0; kj < 4; kj++)
#pragma unroll
        for (int r = 0; r < 4; r++) pm = fmaxf(pm, s[kj][qi][r]);
      pm = fmaxf(pm, __shfl_xor(pm, 16));
      pm = fmaxf(pm, __shfl_xor(pm, 32));
      float mn = fmaxf(m_r[qi], pm);
      float fac = exp2f(m_r[qi] - mn);  // first tile: exp2(-inf)=0
      m_r[qi] = mn;
      float ls = 0.f;
      int prow = 16 * qi + c;
#pragma unroll
      for (int kj = 0; kj < 4; kj++) {
        u16x4 pk;
#pragma unroll
        for (int r = 0; r < 4; r++) {
          float p = exp2f(s[kj][qi][r] - mn);
          ls += p;
          pk[r] = f2b(p);
        }
        int sl = (2 * kj + (g >> 1)) ^ (prow & 7);
        *(u16x4*)(&Ps[w][prow * 64 + sl * 8 + (g & 1) * 4]) = pk;
      }
      ls += __shfl_xor(ls, 16);
      ls += __shfl_xor(ls, 32);
      l_r[qi] = l_r[qi] * fac + ls;
#pragma unroll
      for (int dj = 0; dj < 4; dj++) o[qi][dj] *= fac;
    }

    // O^T += mfma(V^T, P)
#pragma unroll
    for (int ks = 0; ks < 2; ks++) {
      u16x8 vf[4], pf[2];
#pragma unroll
      for (int dj = 0; dj < 4; dj++) vf[dj] = ldsrd(Vs, 16 * dj + c, g + 4 * ks);
#pragma unroll
      for (int qi = 0; qi < 2; qi++) pf[qi] = ldsrd(Ps[w], 16 * qi + c, g + 4 * ks);
#pragma unroll
      for (int qi = 0; qi < 2; qi++)
#pragma unroll
        for (int dj = 0; dj < 4; dj++) o[qi][dj] = mfma16(vf[dj], pf[qi], o[qi][dj]);
    }
    __syncthreads();
  }

#pragma unroll
  for (int qi = 0; qi < 2; qi++) {
    float inv = 1.f / l_r[qi];
#pragma unroll
    for (int dj = 0; dj < 4; dj++) {
      u16x4 ov;
#pragma unroll
      for (int r = 0; r < 4; r++) ov[r] = f2b(o[qi][dj][r] * inv);
      *(u16x4*)(att + (size_t)(q0 + w * 32 + 16 * qi + c) * 1024 + h * 64 + 16 * dj + 4 * g) = ov;
    }
  }
}

extern "C" void kernel_launch(void* const* d_in, const int* in_sizes, int n_in,
                              void* d_out, int out_size, void* d_ws, size_t ws_size,
                              hipStream_t stream) {
  const float* x  = (const float*)d_in[0];
  const float* Wq = (const float*)d_in[1];
  const float* bq = (const float*)d_in[2];
  const float* Wk = (const float*)d_in[3];
  const float* bk = (const float*)d_in[4];
  const float* Wv = (const float*)d_in[5];
  const float* bv = (const float*)d_in[6];
  const float* Wo = (const float*)d_in[7];
  const float* bo = (const float*)d_in[8];
  float* out = (float*)d_out;
  char* ws = (char*)d_ws;

  u16* X16  = (u16*)(ws);                // 8MB x bf16 [4096][1024]; reused as ATT
  u16* WQKV = (u16*)(ws + 8388608);      // 3MB [1536][1024] (Wq;Wk;Wv)
  u16* WO16 = (u16*)(ws + 11534336);     // 2MB [1024][1024]
  u16* QS   = (u16*)(ws + 13631488);     // 8MB scaled Q bf16 [4096][1024]
  u16* KB   = (u16*)(ws + 22020096);     // 2MB K bf16 [4][4096][64]
  u16* VT   = (u16*)(ws + 24117248);     // 2MB V^T bf16 [4][64][4096]
  u16* ATT  = X16;                       // x is dead after QKV gemm

  cast_f32_bf16<<<1024, 256, 0, stream>>>(x, X16, 4096 * 1024 / 4);
  cast_f32_bf16<<<256, 256, 0, stream>>>(Wq, WQKV, 1024 * 1024 / 4);
  cast_f32_bf16<<<64, 256, 0, stream>>>(Wk, WQKV + 1024 * 1024, 256 * 1024 / 4);
  cast_f32_bf16<<<64, 256, 0, stream>>>(Wv, WQKV + 1280 * 1024, 256 * 1024 / 4);
  cast_f32_bf16<<<256, 256, 0, stream>>>(Wo, WO16, 1024 * 1024 / 4);

  gemm_bt<0><<<dim3(12, 32), 256, 0, stream>>>(X16, WQKV, bq, bk, bv, out, QS, KB, VT, 1024);
  attn_fwd<<<dim3(32, 16), 256, 0, stream>>>(QS, KB, VT, ATT);
  gemm_bt<1><<<dim3(8, 32), 256, 0, stream>>>(ATT, WO16, bo, nullptr, nullptr, out,
                                              nullptr, nullptr, nullptr, 1024);
}

// Round 2
// 260.639 us; speedup vs baseline: 1.2727x; 1.2727x over previous
//
#include <hip/hip_runtime.h>
#include <hip/hip_bf16.h>
#include <math.h>

typedef unsigned short u16;
typedef __bf16 bf16;
typedef __bf16 bf16x8 __attribute__((ext_vector_type(8)));
typedef float f32x4 __attribute__((ext_vector_type(4)));
typedef u16 u16x4 __attribute__((ext_vector_type(4)));
typedef u16 u16x8 __attribute__((ext_vector_type(8)));

// scale = 1/sqrt(64) * log2(e)  (folded into Q; softmax uses exp2)
#define QSCALE 0.1803368801111204f

// fp32 -> bf16 (RNE): native cast -> v_cvt_pk_bf16_f32 on gfx950
static __device__ __forceinline__ u16 f2b(float f) {
  return __builtin_bit_cast(u16, (bf16)f);
}

static __device__ __forceinline__ f32x4 mfma16(u16x8 a, u16x8 b, f32x4 c) {
  return __builtin_amdgcn_mfma_f32_16x16x32_bf16(
      __builtin_bit_cast(bf16x8, a), __builtin_bit_cast(bf16x8, b), c, 0, 0, 0);
}

// async global->LDS, 16B per lane; LDS ptr must be wave-uniform
static __device__ __forceinline__ void glds16(const u16* g, u16* l) {
  __builtin_amdgcn_global_load_lds(
      (const __attribute__((address_space(1))) void*)g,
      (__attribute__((address_space(3))) void*)l, 16, 0, 0);
}

#define WAIT_VM0() asm volatile("s_waitcnt vmcnt(0)" ::: "memory")

// Swizzled LDS read: tiles have 64-u16 (128B) rows = 8 slots of 16B, slot ^= row&7
static __device__ __forceinline__ u16x8 ldsrd(const u16* base, int row, int slot) {
  return *(const u16x8*)(base + row * 64 + ((slot ^ (row & 7)) * 8));
}

__global__ void cast_f32_bf16(const float* __restrict__ src, u16* __restrict__ dst, int n4) {
  int i = blockIdx.x * blockDim.x + threadIdx.x;
  int stride = gridDim.x * blockDim.x;
  for (; i < n4; i += stride) {
    f32x4 v = ((const f32x4*)src)[i];
    u16x4 o;
#pragma unroll
    for (int r = 0; r < 4; r++) o[r] = f2b(v[r]);
    ((u16x4*)dst)[i] = o;
  }
}

// C = A @ B^T (+bias). A [M][K] bf16, B [N][K] bf16. 128x128 tile, BK=64, 256 thr.
// 2-phase pipeline: stage(t+1) issued before compute(t); one vmcnt(0)+barrier per step.
// Swapped MFMA: lane holds C^T[n=...+4g+reg][m=...+c] -> packed stores along n.
template<int MODE>
__global__ __launch_bounds__(256, 2) void gemm_bt(
    const u16* __restrict__ A, const u16* __restrict__ B,
    const float* __restrict__ b0, const float* __restrict__ b1,
    const float* __restrict__ b2,
    float* __restrict__ outF,
    u16* __restrict__ qs, u16* __restrict__ kb, u16* __restrict__ vt,
    int K) {
  __shared__ u16 As[2][128 * 64];
  __shared__ u16 Bs[2][128 * 64];
  const int t = threadIdx.x, w = t >> 6, l = t & 63;
  const int c = l & 15, g = l >> 4;
  const int n0 = blockIdx.x * 128, m0 = blockIdx.y * 128;
  const int nrow0 = (w >> 1) * 64, mrow0 = (w & 1) * 64;
  const int srow = l >> 3, sslot = l & 7;

  f32x4 acc[4][4];
  f32x4 z = {0.f, 0.f, 0.f, 0.f};
#pragma unroll
  for (int i = 0; i < 4; i++)
#pragma unroll
    for (int j = 0; j < 4; j++) acc[i][j] = z;

  // prologue: stage step 0 -> buf 0
#pragma unroll
  for (int p = 0; p < 4; p++) {
    int row = p * 32 + w * 8 + srow;
    int ss = sslot ^ (row & 7);
    glds16(A + (size_t)(m0 + row) * K + ss * 8, &As[0][p * 2048 + w * 512]);
    glds16(B + (size_t)(n0 + row) * K + ss * 8, &Bs[0][p * 2048 + w * 512]);
  }
  WAIT_VM0();
  __builtin_amdgcn_s_barrier();

  const int NS = K >> 6;
  for (int st = 0; st < NS; ++st) {
    const int cur = st & 1;
    if (st + 1 < NS) {
      int kt = (st + 1) * 64;
#pragma unroll
      for (int p = 0; p < 4; p++) {
        int row = p * 32 + w * 8 + srow;
        int ss = sslot ^ (row & 7);
        glds16(A + (size_t)(m0 + row) * K + kt + ss * 8, &As[cur ^ 1][p * 2048 + w * 512]);
        glds16(B + (size_t)(n0 + row) * K + kt + ss * 8, &Bs[cur ^ 1][p * 2048 + w * 512]);
      }
    }
    __builtin_amdgcn_s_setprio(1);
#pragma unroll
    for (int ks = 0; ks < 2; ks++) {
      u16x8 af[4], bf[4];
#pragma unroll
      for (int nj = 0; nj < 4; nj++) af[nj] = ldsrd(Bs[cur], nrow0 + 16 * nj + c, g + 4 * ks);
#pragma unroll
      for (int mi = 0; mi < 4; mi++) bf[mi] = ldsrd(As[cur], mrow0 + 16 * mi + c, g + 4 * ks);
#pragma unroll
      for (int nj = 0; nj < 4; nj++)
#pragma unroll
        for (int mi = 0; mi < 4; mi++) acc[nj][mi] = mfma16(af[nj], bf[mi], acc[nj][mi]);
    }
    __builtin_amdgcn_s_setprio(0);
    WAIT_VM0();
    __builtin_amdgcn_s_barrier();
  }

#pragma unroll
  for (int nj = 0; nj < 4; nj++) {
#pragma unroll
    for (int mi = 0; mi < 4; mi++) {
      int n = n0 + nrow0 + 16 * nj + 4 * g;   // 4 consecutive n (reg 0..3)
      int m = m0 + mrow0 + 16 * mi + c;
      f32x4 v = acc[nj][mi];
      if (MODE == 1) {
        f32x4 bb = *(const f32x4*)(b0 + n);
        v += bb;
        *(f32x4*)(outF + (size_t)m * 1024 + n) = v;
      } else {
        if (n < 1024) {              // Q -> scaled bf16
          f32x4 bb = *(const f32x4*)(b0 + n);
          v += bb;
          u16x4 q;
#pragma unroll
          for (int r = 0; r < 4; r++) q[r] = f2b(v[r] * QSCALE);
          *(u16x4*)(qs + (size_t)m * 1024 + n) = q;
        } else if (n < 1280) {       // K -> fp32 d_out + bf16 ws [kh][t][d]
          int nn = n - 1024, khh = nn >> 6, d = nn & 63;
          f32x4 bb = *(const f32x4*)(b1 + nn);
          v += bb;
          *(f32x4*)(outF + (size_t)4194304 + (size_t)(khh * 4096 + m) * 64 + d) = v;
          u16x4 kq;
#pragma unroll
          for (int r = 0; r < 4; r++) kq[r] = f2b(v[r]);
          *(u16x4*)(kb + (size_t)(khh * 4096 + m) * 64 + d) = kq;
        } else {                     // V -> fp32 d_out + bf16 ws TRANSPOSED [kh][d][t]
          int nn = n - 1280, khh = nn >> 6, d = nn & 63;
          f32x4 bb = *(const f32x4*)(b2 + nn);
          v += bb;
          *(f32x4*)(outF + (size_t)5242880 + (size_t)(khh * 4096 + m) * 64 + d) = v;
#pragma unroll
          for (int r = 0; r < 4; r++) vt[(size_t)(khh * 64 + d + r) * 4096 + m] = f2b(v[r]);
        }
      }
    }
  }
}

// Flash attention fwd: grid (64 q-tiles, 16 heads) = 1024 blocks, 256 thr = 4 waves.
// Each wave owns 16 q-rows (lane c = q-row; g = key-slice). Double-buffered K/V,
// 2-phase async pipeline, one raw barrier per KV tile. Defer-max (THR=8).
__global__ __launch_bounds__(256, 4) void attn_fwd(
    const u16* __restrict__ qs, const u16* __restrict__ kb,
    const u16* __restrict__ vt, u16* __restrict__ att) {
  __shared__ u16 Ks[2][64 * 64];   // [key][d] swz
  __shared__ u16 Vs[2][64 * 64];   // [d][key] swz (V^T tile)
  __shared__ u16 Ps[4][16 * 64];   // per-wave [q][key] swz
  const int h = blockIdx.y, kh = h >> 2;
  const int q0 = blockIdx.x * 64;
  const int t = threadIdx.x, w = t >> 6, l = t & 63;
  const int c = l & 15, g = l >> 4;
  const int srow = l >> 3, sslot = l & 7;

  const u16* kbase = kb + (size_t)kh * 4096 * 64;
  const u16* vbase = vt + (size_t)kh * 64 * 4096;

  // Q fragments (B-role): row q0+w*16+c, elems d = 8g+32ks+j (scale pre-folded)
  u16x8 qf[2];
#pragma unroll
  for (int ks = 0; ks < 2; ks++)
    qf[ks] = *(const u16x8*)(qs + (size_t)(q0 + w * 16 + c) * 1024 + h * 64 + g * 8 + ks * 32);

  f32x4 o[4];  // O^T acc: rows d=16dj+4g+reg, col q=c
  f32x4 z = {0.f, 0.f, 0.f, 0.f};
#pragma unroll
  for (int dj = 0; dj < 4; dj++) o[dj] = z;
  float m_r = -INFINITY, l_r = 0.f;

  // prologue: stage tile 0 -> buf 0
#pragma unroll
  for (int p = 0; p < 2; p++) {
    int row = p * 32 + w * 8 + srow;
    int ss = sslot ^ (row & 7);
    glds16(kbase + (size_t)row * 64 + ss * 8, &Ks[0][p * 2048 + w * 512]);
    glds16(vbase + (size_t)row * 4096 + ss * 8, &Vs[0][p * 2048 + w * 512]);
  }
  WAIT_VM0();
  __builtin_amdgcn_s_barrier();

  for (int tt = 0; tt < 64; ++tt) {
    const int cur = tt & 1;
    const u16* KsC = Ks[cur];
    const u16* VsC = Vs[cur];
    if (tt < 63) {
      int kv = (tt + 1) * 64;
#pragma unroll
      for (int p = 0; p < 2; p++) {
        int row = p * 32 + w * 8 + srow;
        int ss = sslot ^ (row & 7);
        glds16(kbase + (size_t)(kv + row) * 64 + ss * 8, &Ks[cur ^ 1][p * 2048 + w * 512]);
        glds16(vbase + (size_t)row * 4096 + kv + ss * 8, &Vs[cur ^ 1][p * 2048 + w * 512]);
      }
    }

    // S^T = mfma(K, Q): lane holds S[q=c][k=16kj+4g+r]
    f32x4 s[4];
#pragma unroll
    for (int kj = 0; kj < 4; kj++) s[kj] = z;
    __builtin_amdgcn_s_setprio(1);
#pragma unroll
    for (int ks = 0; ks < 2; ks++) {
      u16x8 kf[4];
#pragma unroll
      for (int kj = 0; kj < 4; kj++) kf[kj] = ldsrd(KsC, 16 * kj + c, g + 4 * ks);
#pragma unroll
      for (int kj = 0; kj < 4; kj++) s[kj] = mfma16(kf[kj], qf[ks], s[kj]);
    }
    __builtin_amdgcn_s_setprio(0);

    // online softmax (exp2 domain) with defer-max, pack P -> per-wave LDS
    float pm = fmaxf(fmaxf(fmaxf(s[0][0], s[0][1]), fmaxf(s[0][2], s[0][3])),
                     fmaxf(fmaxf(s[1][0], s[1][1]), fmaxf(s[1][2], s[1][3])));
    pm = fmaxf(pm, fmaxf(fmaxf(fmaxf(s[2][0], s[2][1]), fmaxf(s[2][2], s[2][3])),
                         fmaxf(fmaxf(s[3][0], s[3][1]), fmaxf(s[3][2], s[3][3]))));
    pm = fmaxf(pm, __shfl_xor(pm, 16));
    pm = fmaxf(pm, __shfl_xor(pm, 32));
    float fac = 1.f;
    if (!__all(pm - m_r <= 8.0f)) {
      float mn = fmaxf(m_r, pm);
      fac = __builtin_amdgcn_exp2f(m_r - mn);  // first tile: exp2(-inf)=0
      m_r = mn;
#pragma unroll
      for (int dj = 0; dj < 4; dj++) o[dj] *= fac;
    }
    float ls = 0.f;
#pragma unroll
    for (int kj = 0; kj < 4; kj++) {
      u16x4 pk;
#pragma unroll
      for (int r = 0; r < 4; r++) {
        float p = __builtin_amdgcn_exp2f(s[kj][r] - m_r);
        ls += p;
        pk[r] = f2b(p);
      }
      int sl = (2 * kj + (g >> 1)) ^ (c & 7);
      *(u16x4*)(&Ps[w][c * 64 + sl * 8 + (g & 1) * 4]) = pk;
    }
    ls += __shfl_xor(ls, 16);
    ls += __shfl_xor(ls, 32);
    l_r = l_r * fac + ls;

    // O^T += mfma(V^T, P)
    __builtin_amdgcn_s_setprio(1);
#pragma unroll
    for (int ks = 0; ks < 2; ks++) {
      u16x8 vf[4], pf;
#pragma unroll
      for (int dj = 0; dj < 4; dj++) vf[dj] = ldsrd(VsC, 16 * dj + c, g + 4 * ks);
      pf = ldsrd(Ps[w], c, g + 4 * ks);
#pragma unroll
      for (int dj = 0; dj < 4; dj++) o[dj] = mfma16(vf[dj], pf, o[dj]);
    }
    __builtin_amdgcn_s_setprio(0);

    WAIT_VM0();
    __builtin_amdgcn_s_barrier();
  }

  float inv = 1.f / l_r;
#pragma unroll
  for (int dj = 0; dj < 4; dj++) {
    u16x4 ov;
#pragma unroll
    for (int r = 0; r < 4; r++) ov[r] = f2b(o[dj][r] * inv);
    *(u16x4*)(att + (size_t)(q0 + w * 16 + c) * 1024 + h * 64 + 16 * dj + 4 * g) = ov;
  }
}

extern "C" void kernel_launch(void* const* d_in, const int* in_sizes, int n_in,
                              void* d_out, int out_size, void* d_ws, size_t ws_size,
                              hipStream_t stream) {
  const float* x  = (const float*)d_in[0];
  const float* Wq = (const float*)d_in[1];
  const float* bq = (const float*)d_in[2];
  const float* Wk = (const float*)d_in[3];
  const float* bk = (const float*)d_in[4];
  const float* Wv = (const float*)d_in[5];
  const float* bv = (const float*)d_in[6];
  const float* Wo = (const float*)d_in[7];
  const float* bo = (const float*)d_in[8];
  float* out = (float*)d_out;
  char* ws = (char*)d_ws;

  u16* X16  = (u16*)(ws);                // 8MB x bf16 [4096][1024]; reused as ATT
  u16* WQKV = (u16*)(ws + 8388608);      // 3MB [1536][1024] (Wq;Wk;Wv)
  u16* WO16 = (u16*)(ws + 11534336);     // 2MB [1024][1024]
  u16* QS   = (u16*)(ws + 13631488);     // 8MB scaled Q bf16 [4096][1024]
  u16* KB   = (u16*)(ws + 22020096);     // 2MB K bf16 [4][4096][64]
  u16* VT   = (u16*)(ws + 24117248);     // 2MB V^T bf16 [4][64][4096]
  u16* ATT  = X16;                       // x is dead after QKV gemm

  cast_f32_bf16<<<1024, 256, 0, stream>>>(x, X16, 4096 * 1024 / 4);
  cast_f32_bf16<<<256, 256, 0, stream>>>(Wq, WQKV, 1024 * 1024 / 4);
  cast_f32_bf16<<<64, 256, 0, stream>>>(Wk, WQKV + 1024 * 1024, 256 * 1024 / 4);
  cast_f32_bf16<<<64, 256, 0, stream>>>(Wv, WQKV + 1280 * 1024, 256 * 1024 / 4);
  cast_f32_bf16<<<256, 256, 0, stream>>>(Wo, WO16, 1024 * 1024 / 4);

  gemm_bt<0><<<dim3(12, 32), 256, 0, stream>>>(X16, WQKV, bq, bk, bv, out, QS, KB, VT, 1024);
  attn_fwd<<<dim3(64, 16), 256, 0, stream>>>(QS, KB, VT, ATT);
  gemm_bt<1><<<dim3(8, 32), 256, 0, stream>>>(ATT, WO16, bo, nullptr, nullptr, out,
                                              nullptr, nullptr, nullptr, 1024);
}

// Round 3
// 241.200 us; speedup vs baseline: 1.3753x; 1.0806x over previous
//
#include <hip/hip_runtime.h>
#include <hip/hip_bf16.h>
#include <math.h>

typedef unsigned short u16;
typedef unsigned int u32;
typedef __bf16 bf16;
typedef __bf16 bf16x8 __attribute__((ext_vector_type(8)));
typedef float f32x4 __attribute__((ext_vector_type(4)));
typedef float f32x16 __attribute__((ext_vector_type(16)));
typedef u16 u16x2 __attribute__((ext_vector_type(2)));
typedef u16 u16x4 __attribute__((ext_vector_type(4)));
typedef u16 u16x8 __attribute__((ext_vector_type(8)));
typedef u32 u32x4 __attribute__((ext_vector_type(4)));

// scale = 1/sqrt(64) * log2(e)  (folded into Q; softmax uses exp2)
#define QSCALE 0.1803368801111204f

// fp32 -> bf16 (RNE): native cast -> v_cvt_pk_bf16_f32 pairs on gfx950
static __device__ __forceinline__ u16 f2b(float f) {
  return __builtin_bit_cast(u16, (bf16)f);
}
static __device__ __forceinline__ u32 pack2(float a, float b) {
  u16x2 p = { f2b(a), f2b(b) };   // low u16 = a (even k), high = b
  return __builtin_bit_cast(u32, p);
}

static __device__ __forceinline__ f32x4 mfma16(u16x8 a, u16x8 b, f32x4 c) {
  return __builtin_amdgcn_mfma_f32_16x16x32_bf16(
      __builtin_bit_cast(bf16x8, a), __builtin_bit_cast(bf16x8, b), c, 0, 0, 0);
}
static __device__ __forceinline__ f32x16 mfma32(u16x8 a, u16x8 b, f32x16 c) {
  return __builtin_amdgcn_mfma_f32_32x32x16_bf16(
      __builtin_bit_cast(bf16x8, a), __builtin_bit_cast(bf16x8, b), c, 0, 0, 0);
}

// swap a's upper 32 lanes with b's lower 32 lanes (v_permlane32_swap_b32)
static __device__ __forceinline__ void pl32swap(u32& a, u32& b) {
  asm("v_permlane32_swap_b32 %0, %1" : "+v"(a), "+v"(b));
}

// async global->LDS, 16B per lane; LDS ptr must be wave-uniform
static __device__ __forceinline__ void glds16(const u16* g, u16* l) {
  __builtin_amdgcn_global_load_lds(
      (const __attribute__((address_space(1))) void*)g,
      (__attribute__((address_space(3))) void*)l, 16, 0, 0);
}

#define WAIT_VM0() asm volatile("s_waitcnt vmcnt(0)" ::: "memory")

// Swizzled LDS read: tiles have 64-u16 (128B) rows = 8 slots of 16B, slot ^= row&7
static __device__ __forceinline__ u16x8 ldsrd(const u16* base, int row, int slot) {
  return *(const u16x8*)(base + row * 64 + ((slot ^ (row & 7)) * 8));
}

__global__ void cast_f32_bf16(const float* __restrict__ src, u16* __restrict__ dst, int n4) {
  int i = blockIdx.x * blockDim.x + threadIdx.x;
  int stride = gridDim.x * blockDim.x;
  for (; i < n4; i += stride) {
    f32x4 v = ((const f32x4*)src)[i];
    u16x4 o;
#pragma unroll
    for (int r = 0; r < 4; r++) o[r] = f2b(v[r]);
    ((u16x4*)dst)[i] = o;
  }
}

// all four weight matrices in one launch (f32x4 granules)
__global__ void cast_weights(const float* __restrict__ Wq, const float* __restrict__ Wk,
                             const float* __restrict__ Wv, const float* __restrict__ Wo,
                             u16* __restrict__ wqkv, u16* __restrict__ wo16) {
  int i = blockIdx.x * blockDim.x + threadIdx.x;
  int stride = gridDim.x * blockDim.x;
  for (; i < 655360; i += stride) {
    const float* src; u16* dst; int j;
    if (i < 262144)      { src = Wq; dst = wqkv;           j = i; }
    else if (i < 327680) { src = Wk; dst = wqkv + 1048576; j = i - 262144; }
    else if (i < 393216) { src = Wv; dst = wqkv + 1310720; j = i - 327680; }
    else                 { src = Wo; dst = wo16;           j = i - 393216; }
    f32x4 v = ((const f32x4*)src)[j];
    u16x4 o;
#pragma unroll
    for (int r = 0; r < 4; r++) o[r] = f2b(v[r]);
    ((u16x4*)dst)[j] = o;
  }
}

// V [kh][t][d] bf16 -> V^T [kh][d][t] bf16, 64x64 LDS tiles
__global__ void transpose_v(const u16* __restrict__ vb, u16* __restrict__ vt) {
  __shared__ u16 T[64][72];
  const int kh = blockIdx.y;
  const int t0 = blockIdx.x * 64;
  const int tid = threadIdx.x;
  const int r = tid >> 2, c0 = (tid & 3) * 16;
  const u16* src = vb + ((size_t)kh * 4096 + t0 + r) * 64 + c0;
  *(u16x8*)&T[r][c0] = *(const u16x8*)src;
  *(u16x8*)&T[r][c0 + 8] = *(const u16x8*)(src + 8);
  __syncthreads();
  const int d = tid >> 2, j0 = (tid & 3) * 16;
  u16x8 o0, o1;
#pragma unroll
  for (int j = 0; j < 8; j++) o0[j] = T[j0 + j][d];
#pragma unroll
  for (int j = 0; j < 8; j++) o1[j] = T[j0 + 8 + j][d];
  u16* dst = vt + ((size_t)kh * 64 + d) * 4096 + t0 + j0;
  *(u16x8*)dst = o0;
  *(u16x8*)(dst + 8) = o1;
}

// C = A @ B^T (+bias). A [M][K] bf16, B [N][K] bf16. 128x128 tile, BK=64, 256 thr.
// 2-phase pipeline: stage(t+1) issued before compute(t); one vmcnt(0)+barrier per step.
// Swapped MFMA: lane holds C^T[n=...+4g+reg][m=...+c] -> packed stores along n.
template<int MODE>
__global__ __launch_bounds__(256, 2) void gemm_bt(
    const u16* __restrict__ A, const u16* __restrict__ B,
    const float* __restrict__ b0, const float* __restrict__ b1,
    const float* __restrict__ b2,
    float* __restrict__ outF,
    u16* __restrict__ qs, u16* __restrict__ kb, u16* __restrict__ vb,
    int K) {
  __shared__ u16 As[2][128 * 64];
  __shared__ u16 Bs[2][128 * 64];
  const int t = threadIdx.x, w = t >> 6, l = t & 63;
  const int c = l & 15, g = l >> 4;
  const int n0 = blockIdx.x * 128, m0 = blockIdx.y * 128;
  const int nrow0 = (w >> 1) * 64, mrow0 = (w & 1) * 64;
  const int srow = l >> 3, sslot = l & 7;

  f32x4 acc[4][4];
  f32x4 z = {0.f, 0.f, 0.f, 0.f};
#pragma unroll
  for (int i = 0; i < 4; i++)
#pragma unroll
    for (int j = 0; j < 4; j++) acc[i][j] = z;

  // prologue: stage step 0 -> buf 0
#pragma unroll
  for (int p = 0; p < 4; p++) {
    int row = p * 32 + w * 8 + srow;
    int ss = sslot ^ (row & 7);
    glds16(A + (size_t)(m0 + row) * K + ss * 8, &As[0][p * 2048 + w * 512]);
    glds16(B + (size_t)(n0 + row) * K + ss * 8, &Bs[0][p * 2048 + w * 512]);
  }
  WAIT_VM0();
  __builtin_amdgcn_s_barrier();

  const int NS = K >> 6;
  for (int st = 0; st < NS; ++st) {
    const int cur = st & 1;
    if (st + 1 < NS) {
      int kt = (st + 1) * 64;
#pragma unroll
      for (int p = 0; p < 4; p++) {
        int row = p * 32 + w * 8 + srow;
        int ss = sslot ^ (row & 7);
        glds16(A + (size_t)(m0 + row) * K + kt + ss * 8, &As[cur ^ 1][p * 2048 + w * 512]);
        glds16(B + (size_t)(n0 + row) * K + kt + ss * 8, &Bs[cur ^ 1][p * 2048 + w * 512]);
      }
    }
    __builtin_amdgcn_s_setprio(1);
#pragma unroll
    for (int ks = 0; ks < 2; ks++) {
      u16x8 af[4], bf[4];
#pragma unroll
      for (int nj = 0; nj < 4; nj++) af[nj] = ldsrd(Bs[cur], nrow0 + 16 * nj + c, g + 4 * ks);
#pragma unroll
      for (int mi = 0; mi < 4; mi++) bf[mi] = ldsrd(As[cur], mrow0 + 16 * mi + c, g + 4 * ks);
#pragma unroll
      for (int nj = 0; nj < 4; nj++)
#pragma unroll
        for (int mi = 0; mi < 4; mi++) acc[nj][mi] = mfma16(af[nj], bf[mi], acc[nj][mi]);
    }
    __builtin_amdgcn_s_setprio(0);
    WAIT_VM0();
    __builtin_amdgcn_s_barrier();
  }

#pragma unroll
  for (int nj = 0; nj < 4; nj++) {
#pragma unroll
    for (int mi = 0; mi < 4; mi++) {
      int n = n0 + nrow0 + 16 * nj + 4 * g;   // 4 consecutive n (reg 0..3)
      int m = m0 + mrow0 + 16 * mi + c;
      f32x4 v = acc[nj][mi];
      if (MODE == 1) {
        f32x4 bb = *(const f32x4*)(b0 + n);
        v += bb;
        *(f32x4*)(outF + (size_t)m * 1024 + n) = v;
      } else {
        if (n < 1024) {              // Q -> scaled bf16
          f32x4 bb = *(const f32x4*)(b0 + n);
          v += bb;
          u16x4 q;
#pragma unroll
          for (int r = 0; r < 4; r++) q[r] = f2b(v[r] * QSCALE);
          *(u16x4*)(qs + (size_t)m * 1024 + n) = q;
        } else if (n < 1280) {       // K -> fp32 d_out + bf16 ws [kh][t][d]
          int nn = n - 1024, khh = nn >> 6, d = nn & 63;
          f32x4 bb = *(const f32x4*)(b1 + nn);
          v += bb;
          *(f32x4*)(outF + (size_t)4194304 + (size_t)(khh * 4096 + m) * 64 + d) = v;
          u16x4 kq;
#pragma unroll
          for (int r = 0; r < 4; r++) kq[r] = f2b(v[r]);
          *(u16x4*)(kb + (size_t)(khh * 4096 + m) * 64 + d) = kq;
        } else {                     // V -> fp32 d_out + bf16 ws [kh][t][d] (coalesced)
          int nn = n - 1280, khh = nn >> 6, d = nn & 63;
          f32x4 bb = *(const f32x4*)(b2 + nn);
          v += bb;
          *(f32x4*)(outF + (size_t)5242880 + (size_t)(khh * 4096 + m) * 64 + d) = v;
          u16x4 vq;
#pragma unroll
          for (int r = 0; r < 4; r++) vq[r] = f2b(v[r]);
          *(u16x4*)(vb + (size_t)(khh * 4096 + m) * 64 + d) = vq;
        }
      }
    }
  }
}

// Flash attention fwd, 32x32x16 MFMA: grid (32 q-tiles, 16 heads), 256 thr = 4 waves.
// Wave owns 32 q-rows (col = lane&31). Swapped QK^T -> S^T[k][q] lane-local; P goes
// register->register into the PV B-frag via v_permlane32_swap (no LDS for P).
// l accumulated by a ones-MFMA reusing the PV B-frag. Defer-max THR=8.
__global__ __launch_bounds__(256, 2) void attn_fwd(
    const u16* __restrict__ qs, const u16* __restrict__ kb,
    const u16* __restrict__ vt, u16* __restrict__ att) {
  __shared__ u16 Ks[2][64 * 64];   // [key][d] swz
  __shared__ u16 Vs[2][64 * 64];   // [d][key] swz (V^T tile)
  const int h = blockIdx.y, kh = h >> 2;
  const int q0 = blockIdx.x * 128;
  const int t = threadIdx.x, w = t >> 6, l = t & 63;
  const int ql = l & 31, hh = l >> 5;
  const int srow = l >> 3, sslot = l & 7;

  const u16* kbase = kb + (size_t)kh * 262144;
  const u16* vbase = vt + (size_t)kh * 262144;

  // Q fragments (B-role): row q = q0+w*32+ql, d = 16ks + 8hh + j (scale pre-folded)
  u16x8 qf[4];
#pragma unroll
  for (int ks = 0; ks < 4; ks++)
    qf[ks] = *(const u16x8*)(qs + (size_t)(q0 + w * 32 + ql) * 1024 + h * 64 + ks * 16 + hh * 8);

  u16x8 onesf;
#pragma unroll
  for (int j = 0; j < 8; j++) onesf[j] = 0x3F80;  // bf16 1.0

  f32x16 o0v, o1v, lacc;
#pragma unroll
  for (int i = 0; i < 16; i++) { o0v[i] = 0.f; o1v[i] = 0.f; lacc[i] = 0.f; }
  float m_r = -INFINITY;

  // prologue: stage tile 0 -> buf 0
#pragma unroll
  for (int p = 0; p < 2; p++) {
    int row = p * 32 + w * 8 + srow;
    int ss = sslot ^ (row & 7);
    glds16(kbase + (size_t)row * 64 + ss * 8, &Ks[0][p * 2048 + w * 512]);
    glds16(vbase + (size_t)row * 4096 + ss * 8, &Vs[0][p * 2048 + w * 512]);
  }
  WAIT_VM0();
  __builtin_amdgcn_s_barrier();

  for (int tt = 0; tt < 64; ++tt) {
    const int cur = tt & 1;
    const u16* KsC = Ks[cur];
    const u16* VsC = Vs[cur];
    if (tt < 63) {
      int kv = (tt + 1) * 64;
#pragma unroll
      for (int p = 0; p < 2; p++) {
        int row = p * 32 + w * 8 + srow;
        int ss = sslot ^ (row & 7);
        glds16(kbase + (size_t)(kv + row) * 64 + ss * 8, &Ks[cur ^ 1][p * 2048 + w * 512]);
        glds16(vbase + (size_t)row * 4096 + kv + ss * 8, &Vs[cur ^ 1][p * 2048 + w * 512]);
      }
    }

    // S^T = mfma(K, Q): lane holds S[q=ql][k = 32kj + (reg&3)+8(reg>>2)+4hh]
    f32x16 sA, sB;
#pragma unroll
    for (int i = 0; i < 16; i++) { sA[i] = 0.f; sB[i] = 0.f; }
    __builtin_amdgcn_s_setprio(1);
#pragma unroll
    for (int ks = 0; ks < 4; ks++) {
      u16x8 kf0 = ldsrd(KsC, ql, 2 * ks + hh);
      u16x8 kf1 = ldsrd(KsC, 32 + ql, 2 * ks + hh);
      sA = mfma32(kf0, qf[ks], sA);
      sB = mfma32(kf1, qf[ks], sB);
    }
    __builtin_amdgcn_s_setprio(0);

    // row max (own 32 values, tree) + partner half via lane^32
    float mx[16];
#pragma unroll
    for (int i = 0; i < 16; i++) mx[i] = fmaxf(sA[i], sB[i]);
#pragma unroll
    for (int stp = 8; stp > 0; stp >>= 1)
#pragma unroll
      for (int i = 0; i < stp; i++) mx[i] = fmaxf(mx[i], mx[i + stp]);
    float pm = fmaxf(mx[0], __shfl_xor(mx[0], 32));

    if (!__all(pm - m_r <= 8.0f)) {       // defer-max (THR=8)
      float mn = fmaxf(m_r, pm);
      float fac = __builtin_amdgcn_exp2f(m_r - mn);  // first tile: 0
      m_r = mn;
      o0v *= fac; o1v *= fac; lacc *= fac;
    }

    // P = exp2(S - m), packed bf16 pairs (8 u32 words per 32-k block)
    u32 pw0[8], pw1[8];
#pragma unroll
    for (int i = 0; i < 8; i++) {
      pw0[i] = pack2(__builtin_amdgcn_exp2f(sA[2 * i] - m_r),
                     __builtin_amdgcn_exp2f(sA[2 * i + 1] - m_r));
      pw1[i] = pack2(__builtin_amdgcn_exp2f(sB[2 * i] - m_r),
                     __builtin_amdgcn_exp2f(sB[2 * i + 1] - m_r));
    }

    // PV + l: per 16-k step build B-frag from registers via permlane32_swap
    __builtin_amdgcn_s_setprio(1);
#pragma unroll
    for (int t4 = 0; t4 < 4; t4++) {
      u32 a0, a1, b0, b1;
      if (t4 == 0)      { a0 = pw0[0]; a1 = pw0[1]; b0 = pw0[2]; b1 = pw0[3]; }
      else if (t4 == 1) { a0 = pw0[4]; a1 = pw0[5]; b0 = pw0[6]; b1 = pw0[7]; }
      else if (t4 == 2) { a0 = pw1[0]; a1 = pw1[1]; b0 = pw1[2]; b1 = pw1[3]; }
      else              { a0 = pw1[4]; a1 = pw1[5]; b0 = pw1[6]; b1 = pw1[7]; }
      pl32swap(a0, b0);
      pl32swap(a1, b1);
      u32x4 pv4 = {a0, a1, b0, b1};
      u16x8 pf = __builtin_bit_cast(u16x8, pv4);
      u16x8 vf0 = ldsrd(VsC, ql, 2 * t4 + hh);
      u16x8 vf1 = ldsrd(VsC, 32 + ql, 2 * t4 + hh);
      o0v = mfma32(vf0, pf, o0v);
      o1v = mfma32(vf1, pf, o1v);
      lacc = mfma32(onesf, pf, lacc);
    }
    __builtin_amdgcn_s_setprio(0);

    WAIT_VM0();
    __builtin_amdgcn_s_barrier();
  }

  float inv = 1.f / lacc[0];
  const size_t obase = (size_t)(q0 + w * 32 + ql) * 1024 + h * 64;
#pragma unroll
  for (int dj = 0; dj < 2; dj++)
#pragma unroll
    for (int rq = 0; rq < 4; rq++) {
      u16x4 ov;
#pragma unroll
      for (int r = 0; r < 4; r++)
        ov[r] = f2b((dj ? o1v[rq * 4 + r] : o0v[rq * 4 + r]) * inv);
      *(u16x4*)(att + obase + dj * 32 + rq * 8 + hh * 4) = ov;
    }
}

extern "C" void kernel_launch(void* const* d_in, const int* in_sizes, int n_in,
                              void* d_out, int out_size, void* d_ws, size_t ws_size,
                              hipStream_t stream) {
  const float* x  = (const float*)d_in[0];
  const float* Wq = (const float*)d_in[1];
  const float* bq = (const float*)d_in[2];
  const float* Wk = (const float*)d_in[3];
  const float* bk = (const float*)d_in[4];
  const float* Wv = (const float*)d_in[5];
  const float* bv = (const float*)d_in[6];
  const float* Wo = (const float*)d_in[7];
  const float* bo = (const float*)d_in[8];
  float* out = (float*)d_out;
  char* ws = (char*)d_ws;

  u16* X16  = (u16*)(ws);                // 8MB x bf16 [4096][1024]; reused as ATT
  u16* WQKV = (u16*)(ws + 8388608);      // 3MB [1536][1024]; dead after gemm<0>
  u16* VT   = (u16*)(ws + 8388608);      // 2MB V^T bf16 [4][64][4096] (aliases WQKV)
  u16* WO16 = (u16*)(ws + 11534336);     // 2MB [1024][1024]
  u16* QS   = (u16*)(ws + 13631488);     // 8MB scaled Q bf16 [4096][1024]
  u16* KB   = (u16*)(ws + 22020096);     // 2MB K bf16 [4][4096][64]
  u16* VB   = (u16*)(ws + 24117248);     // 2MB V bf16 [4][4096][64]
  u16* ATT  = X16;                       // x is dead after QKV gemm

  cast_f32_bf16<<<1024, 256, 0, stream>>>(x, X16, 4096 * 1024 / 4);
  cast_weights<<<512, 256, 0, stream>>>(Wq, Wk, Wv, Wo, WQKV, WO16);

  gemm_bt<0><<<dim3(12, 32), 256, 0, stream>>>(X16, WQKV, bq, bk, bv, out, QS, KB, VB, 1024);
  transpose_v<<<dim3(64, 4), 256, 0, stream>>>(VB, VT);
  attn_fwd<<<dim3(32, 16), 256, 0, stream>>>(QS, KB, VT, ATT);
  gemm_bt<1><<<dim3(8, 32), 256, 0, stream>>>(ATT, WO16, bo, nullptr, nullptr, out,
                                              nullptr, nullptr, nullptr, 1024);
}